// Round 1
// baseline (226.379 us; speedup 1.0000x reference)
//
#include <hip/hip_runtime.h>
#include <math.h>

// Problem geometry (fixed by reference)
#define NB 16
#define NC 64
#define NH 64
#define NW 64
#define NK 1024
#define ND 64
#define NPTS (NB*NH*NW)          // 65536
#define QOUT_SZ (NB*NC*NH*NW)    // 4194304
#define LOSS_OFF QOUT_SZ
#define IDX_OFF  (QOUT_SZ + 1)
#define PERP_OFF (QOUT_SZ + 1 + NPTS)

// ws layout (floats): [0,1024) esq, [1024,2048) hist, [2048,3072) loss partials
#define WS_ESQ  0
#define WS_HIST 1024
#define WS_LOSS 2048

// ---------------------------------------------------------------------------
// Prep: esq[k] = sum_d e[k][d]^2 ; zero histogram. Grid 4 x 256.
// ---------------------------------------------------------------------------
__global__ void vq_prep(const float* __restrict__ emb, float* __restrict__ ws) {
    int k = blockIdx.x * 256 + threadIdx.x;     // 0..1023
    const float4* e4 = (const float4*)emb;
    float s = 0.f;
#pragma unroll
    for (int i = 0; i < 16; ++i) {
        float4 v = e4[k*16 + i];
        s = fmaf(v.x, v.x, s);
        s = fmaf(v.y, v.y, s);
        s = fmaf(v.z, v.z, s);
        s = fmaf(v.w, v.w, s);
    }
    ws[WS_ESQ + k] = s;
    ws[WS_HIST + k] = 0.f;
}

// ---------------------------------------------------------------------------
// Main: one block per (b,h) row (64 points along w). 256 threads.
// Register-blocked 4 points x 8 codes per thread; fp32 FMA; fused argmin,
// quantized gather-write, loss partial, histogram, index write.
// ---------------------------------------------------------------------------
__launch_bounds__(256)
__global__ void vq_main(const float* __restrict__ z,
                        const float* __restrict__ emb,
                        float* __restrict__ ws,
                        float* __restrict__ out) {
    __shared__ float zs[ND * 64];        // [d][w]  16 KB
    __shared__ float es[ND * 132];       // [d][k_local] padded stride 132, 33 KB
    __shared__ int   idxs[64];
    __shared__ float redw[4];

    const int tid = threadIdx.x;
    const int bh  = blockIdx.x;          // b*64 + h
    const int b   = bh >> 6;
    const int h   = bh & 63;
    const int w   = tid & 63;            // staging / epilogue lane role
    const int cq  = tid >> 6;            // 0..3

    // ---- stage z tile: zs[c][w] = z[b][c][h][w], coalesced over w ----
    {
        const float* zp = z + (size_t)b * (NC*NH*NW) + (size_t)h * NW + w;
#pragma unroll
        for (int i = 0; i < 16; ++i) {
            int c = cq * 16 + i;
            zs[c*64 + w] = zp[(size_t)c * (NH*NW)];
        }
    }

    const int tx = tid & 15;             // point group: points tx*4 .. tx*4+3
    const int ty = tid >> 4;             // code group: 8 codes per chunk

    float minv[4] = {3.4e38f, 3.4e38f, 3.4e38f, 3.4e38f};
    int   mini[4] = {0, 0, 0, 0};

    const float4* e4 = (const float4*)emb;

    for (int ch = 0; ch < 8; ++ch) {
        __syncthreads();                 // es readers of prev chunk done (also covers zs stage)
        // ---- stage 128 codes transposed: es[d][kl] ----
#pragma unroll
        for (int i = 0; i < 8; ++i) {
            int j  = tid + 256*i;        // 0..2047
            int kl = j >> 4;             // 0..127
            int dv = j & 15;             // float4 index along d
            float4 v = e4[(ch*128 + kl)*16 + dv];
            es[(dv*4+0)*132 + kl] = v.x;
            es[(dv*4+1)*132 + kl] = v.y;
            es[(dv*4+2)*132 + kl] = v.z;
            es[(dv*4+3)*132 + kl] = v.w;
        }
        __syncthreads();

        float acc[4][8];
#pragma unroll
        for (int p = 0; p < 4; ++p)
#pragma unroll
            for (int q = 0; q < 8; ++q) acc[p][q] = 0.f;

#pragma unroll 4
        for (int d = 0; d < ND; ++d) {
            float4 zr = *(const float4*)&zs[d*64  + tx*4];
            float4 ea = *(const float4*)&es[d*132 + ty*8];
            float4 eb = *(const float4*)&es[d*132 + ty*8 + 4];
            float zz[4] = {zr.x, zr.y, zr.z, zr.w};
            float ee[8] = {ea.x, ea.y, ea.z, ea.w, eb.x, eb.y, eb.z, eb.w};
#pragma unroll
            for (int p = 0; p < 4; ++p)
#pragma unroll
                for (int q = 0; q < 8; ++q)
                    acc[p][q] = fmaf(zz[p], ee[q], acc[p][q]);
        }

        // ---- distance + running argmin (ascending k, strict <) ----
        int kbase = ch*128 + ty*8;
        float4 q0 = *(const float4*)&ws[WS_ESQ + kbase];
        float4 q1 = *(const float4*)&ws[WS_ESQ + kbase + 4];
        float eq[8] = {q0.x, q0.y, q0.z, q0.w, q1.x, q1.y, q1.z, q1.w};
#pragma unroll
        for (int q = 0; q < 8; ++q) {
#pragma unroll
            for (int p = 0; p < 4; ++p) {
                float dist = fmaf(-2.f, acc[p][q], eq[q]);
                if (dist < minv[p]) { minv[p] = dist; mini[p] = kbase + q; }
            }
        }
    }

    // ---- block argmin reduce across the 16 code-groups (reuse es) ----
    __syncthreads();
    float* mval = es;                    // [64 points][16 groups]
    int*   midx = (int*)(es + 1024);
#pragma unroll
    for (int p = 0; p < 4; ++p) {
        int pt = tx*4 + p;
        mval[pt*16 + ty] = minv[p];
        midx[pt*16 + ty] = mini[p];
    }
    __syncthreads();
    if (tid < 64) {
        float bv = mval[tid*16];
        int   bi = midx[tid*16];
#pragma unroll
        for (int t = 1; t < 16; ++t) {
            float v  = mval[tid*16 + t];
            int   ii = midx[tid*16 + t];
            if (v < bv || (v == bv && ii < bi)) { bv = v; bi = ii; }  // np first-occurrence
        }
        idxs[tid] = bi;
        atomicAdd(&ws[WS_HIST + bi], 1.0f);               // exact int counts: deterministic
        out[IDX_OFF + bh*64 + tid] = (float)bi;
    }
    __syncthreads();

    // ---- epilogue: quantized write (coalesced over w) + loss partial ----
    int idx = idxs[w];
    float lsum = 0.f;
    float* outq = out + (size_t)b * (NC*NH*NW) + (size_t)h * NW + w;
#pragma unroll
    for (int i = 0; i < 16; ++i) {
        int c = cq + i*4;
        float qv = emb[idx*ND + c];      // gather, L2-hot (emb = 256 KB)
        float zv = zs[c*64 + w];
        outq[(size_t)c * (NH*NW)] = qv;
        float df = qv - zv;
        lsum = fmaf(df, df, lsum);
    }
#pragma unroll
    for (int off = 32; off > 0; off >>= 1)
        lsum += __shfl_xor(lsum, off, 64);
    if ((tid & 63) == 0) redw[tid >> 6] = lsum;
    __syncthreads();
    if (tid == 0)
        ws[WS_LOSS + bh] = redw[0] + redw[1] + redw[2] + redw[3];
}

// ---------------------------------------------------------------------------
// Finalize: loss scalar + perplexity. 1 block x 1024 threads, fixed-order tree.
// ---------------------------------------------------------------------------
__global__ void vq_fin(const float* __restrict__ ws, float* __restrict__ out) {
    __shared__ float sh[1024];
    __shared__ float sl[1024];
    int t = threadIdx.x;
    float hc = ws[WS_HIST + t];
    float p  = hc * (1.0f / (float)NPTS);
    sh[t] = p * logf(p + 1e-10f);
    sl[t] = ws[WS_LOSS + t];
    __syncthreads();
    for (int s = 512; s > 0; s >>= 1) {
        if (t < s) { sh[t] += sh[t+s]; sl[t] += sl[t+s]; }
        __syncthreads();
    }
    if (t == 0) {
        out[LOSS_OFF] = 0.25f * sl[0] / (float)QOUT_SZ;
        out[PERP_OFF] = expf(-sh[0]);
    }
}

extern "C" void kernel_launch(void* const* d_in, const int* in_sizes, int n_in,
                              void* d_out, int out_size, void* d_ws, size_t ws_size,
                              hipStream_t stream) {
    const float* z   = (const float*)d_in[0];   // [16,64,64,64] fp32 NCHW
    const float* emb = (const float*)d_in[1];   // [1024,64] fp32
    float* out = (float*)d_out;
    float* ws  = (float*)d_ws;

    vq_prep<<<4, 256, 0, stream>>>(emb, ws);
    vq_main<<<NB*NH, 256, 0, stream>>>(z, emb, ws, out);
    vq_fin<<<1, 1024, 0, stream>>>(ws, out);
}

// Round 2
// 74.177 us; speedup vs baseline: 3.0519x; 3.0519x over previous
//
#include <hip/hip_runtime.h>
#include <math.h>

// ---------------------------------------------------------------------------
// VQ-VAE eval forward.  N=65536 points x K=1024 codes x D=64, fp32 in/out.
// Strategy: distances via f16x2 split-precision MFMA (32x32x16_f16):
//   z = zh + 2^-12 * zl',  e = eh + 2^-12 * el'   (lo parts pre-scaled by 4096
//   so they stay f16-normal; dropped ll term ~2^-24 == fp32 rounding class)
//   argmin key m = (zh.eh - esq/2) + 2^-12 * (zh.el' + zl'.eh)   [maximize]
// esq/2 is folded into the hh-accumulator init, so the per-element epilogue is
// 1 fma + cmp + 2 cndmask.
// ---------------------------------------------------------------------------

#define QOUT_SZ  4194304            // 16*64*64*64
#define LOSS_OFF QOUT_SZ
#define IDX_OFF  (QOUT_SZ + 1)
#define PERP_OFF (QOUT_SZ + 1 + 65536)

typedef _Float16 f16x8 __attribute__((ext_vector_type(8)));
typedef _Float16 f16x4 __attribute__((ext_vector_type(4)));
typedef float    f32x16 __attribute__((ext_vector_type(16)));

// ws byte offsets
#define WS_EHI   0          // _Float16[65536]  (128 KB)   e hi split
#define WS_ELO   131072     // _Float16[65536]  (128 KB)   e lo split (x4096)
#define WS_ESQ   262144     // float[1024]
#define WS_HIST  266240     // float[1024]
#define WS_LOSS  270336     // float[512]

// ---------------------------------------------------------------------------
// Split-convert embedding: ehi = f16(e), elo = f16((e - ehi) * 4096)
// grid 64 x 256, one float4 per thread.
// ---------------------------------------------------------------------------
__global__ void vq_conv(const float* __restrict__ emb,
                        _Float16* __restrict__ ehi, _Float16* __restrict__ elo) {
    int g = blockIdx.x * 256 + threadIdx.x;       // 0..16383 float4 units
    float4 v = ((const float4*)emb)[g];
    float xs[4] = {v.x, v.y, v.z, v.w};
    f16x4 hi, lo;
#pragma unroll
    for (int j = 0; j < 4; ++j) {
        _Float16 h = (_Float16)xs[j];
        hi[j] = h;
        lo[j] = (_Float16)((xs[j] - (float)h) * 4096.0f);
    }
    ((f16x4*)ehi)[g] = hi;
    ((f16x4*)elo)[g] = lo;
}

// ---------------------------------------------------------------------------
// esq[k] = ||e_k||^2 ; zero histogram. grid 4 x 256.
// ---------------------------------------------------------------------------
__global__ void vq_prep(const float* __restrict__ emb,
                        float* __restrict__ esq, float* __restrict__ hist) {
    int k = blockIdx.x * 256 + threadIdx.x;
    const float4* e4 = (const float4*)emb;
    float s = 0.f;
#pragma unroll
    for (int i = 0; i < 16; ++i) {
        float4 v = e4[k*16 + i];
        s = fmaf(v.x, v.x, s); s = fmaf(v.y, v.y, s);
        s = fmaf(v.z, v.z, s); s = fmaf(v.w, v.w, s);
    }
    esq[k]  = s;
    hist[k] = 0.f;
}

// ---------------------------------------------------------------------------
// Main: 512 blocks x 256 threads (4 waves).  Block owns 128 points (2 bh rows);
// wave owns 32 points.  k loop: 8 chunks x 128 codes; per chunk 4 tiles of 32
// codes; per tile 12 MFMA (4 d-steps x {hh, h*lo, lo*h}).
// LDS: zs fp32 [128][68] (34.8 KB) + {ehi|elo|esq chunk, 33 KB, XOR-swizzled}
// overlaid later by the argmin candidate arrays.
// ---------------------------------------------------------------------------
__launch_bounds__(256, 2)
__global__ void vq_main(const float* __restrict__ z,
                        const float* __restrict__ emb,
                        const _Float16* __restrict__ gehi,
                        const _Float16* __restrict__ gelo,
                        const float* __restrict__ gesq,
                        float* __restrict__ hist,
                        float* __restrict__ lossp,
                        float* __restrict__ out) {
    __shared__ float zs[128*68];                       // [point][d], pad 68
    __shared__ __align__(16) char smem[33792];         // e-chunk / candidates
    __shared__ int   idxs[128];
    __shared__ float redw[4];

    _Float16* ehi = (_Float16*)smem;                   // [128 codes][64] swz
    _Float16* elo = (_Float16*)(smem + 16384);
    float*    esqs = (float*)(smem + 32768);           // [128]
    float*    cv  = (float*)smem;                      // [128][33] (overlay)
    int*      ci  = (int*)(smem + 16896);

    const int tid  = threadIdx.x;
    const int blk  = blockIdx.x;          // 512
    const int bh0  = blk * 2;
    const int b    = bh0 >> 6;
    const int h0   = bh0 & 63;
    const int lane = tid & 63;
    const int wv   = tid >> 6;            // wave 0..3
    const int arow = lane & 31;           // point row in wave tile / B col
    const int kg   = lane >> 5;           // k-group 0..1

    // ---- stage z: zs[half*64+w][c] = z[b][c][h0+half][w] ----
    const float* zb = z + (size_t)b * (64*64*64);
#pragma unroll
    for (int i = 0; i < 8; ++i) {
        int j  = tid + 256*i;             // 0..2047 float4 units
        int w4 = j & 15;
        int u  = j >> 4;
        int hf = u & 1;
        int c  = u >> 1;
        float4 v = *(const float4*)(zb + (size_t)c*4096 + (h0+hf)*64 + w4*4);
        int p = hf*64 + w4*4;
        zs[(p+0)*68 + c] = v.x;
        zs[(p+1)*68 + c] = v.y;
        zs[(p+2)*68 + c] = v.z;
        zs[(p+3)*68 + c] = v.w;
    }
    __syncthreads();

    // ---- build A fragments (z splits) in registers, once ----
    const int pglob = wv*32 + arow;
    f16x8 Ah[4], Al[4];
#pragma unroll
    for (int s = 0; s < 4; ++s) {
        const float* zp = &zs[pglob*68 + s*16 + kg*8];
        float4 x0 = *(const float4*)(zp);
        float4 x1 = *(const float4*)(zp + 4);
        float xs8[8] = {x0.x,x0.y,x0.z,x0.w,x1.x,x1.y,x1.z,x1.w};
#pragma unroll
        for (int j = 0; j < 8; ++j) {
            _Float16 h = (_Float16)xs8[j];
            Ah[s][j] = h;
            Al[s][j] = (_Float16)((xs8[j] - (float)h) * 4096.0f);
        }
    }

    float best[16];
    int   besti[16];
#pragma unroll
    for (int r = 0; r < 16; ++r) { best[r] = -3.4e38f; besti[r] = 0; }

    // ---- k loop: 8 chunks of 128 codes ----
    for (int ch = 0; ch < 8; ++ch) {
        __syncthreads();                  // previous chunk's reads done
        // stage e chunk (hi, lo) with XOR swizzle on 16B units
#pragma unroll
        for (int i = 0; i < 4; ++i) {
            int u    = tid + 256*i;       // 0..1023
            int c    = u >> 3;            // local code
            int dblk = u & 7;             // 16B unit in row
            size_t gb = ((size_t)(ch*128 + c))*128 + dblk*16;
            int    lb = c*128 + ((dblk*16) ^ ((c & 7) << 4));
            *(uint4*)((char*)ehi + lb) = *(const uint4*)((const char*)gehi + gb);
            *(uint4*)((char*)elo + lb) = *(const uint4*)((const char*)gelo + gb);
        }
        if (tid < 128) esqs[tid] = gesq[ch*128 + tid];
        __syncthreads();

        // 4 tiles of 32 codes
#pragma unroll
        for (int t = 0; t < 4; ++t) {
            const int ccol = t*32 + arow;            // local code for this lane
            const int kidx = ch*128 + ccol;          // global code index
            const float e2 = esqs[ccol] * -0.5f;
            f32x16 acc_hh, acc_x;
#pragma unroll
            for (int r = 0; r < 16; ++r) { acc_hh[r] = e2; acc_x[r] = 0.f; }
#pragma unroll
            for (int s = 0; s < 4; ++s) {
                int boff = (s*32 + kg*16) ^ ((ccol & 7) << 4);
                f16x8 Bh = *(const f16x8*)((const char*)ehi + ccol*128 + boff);
                f16x8 Bl = *(const f16x8*)((const char*)elo + ccol*128 + boff);
                acc_hh = __builtin_amdgcn_mfma_f32_32x32x16_f16(Ah[s], Bh, acc_hh, 0, 0, 0);
                acc_x  = __builtin_amdgcn_mfma_f32_32x32x16_f16(Ah[s], Bl, acc_x,  0, 0, 0);
                acc_x  = __builtin_amdgcn_mfma_f32_32x32x16_f16(Al[s], Bh, acc_x,  0, 0, 0);
            }
#pragma unroll
            for (int r = 0; r < 16; ++r) {
                float m = fmaf(0x1p-12f, acc_x[r], acc_hh[r]);   // dot - esq/2
                if (m > best[r]) { best[r] = m; besti[r] = kidx; }
            }
        }
    }

    // ---- dump per-lane candidates, scan per point ----
    __syncthreads();                      // done with ehi/elo/esqs
#pragma unroll
    for (int r = 0; r < 16; ++r) {
        int row = (r & 3) + 8*(r >> 2) + 4*kg;       // 0..31
        int p   = wv*32 + row;
        cv[p*33 + arow] = best[r];
        ci[p*33 + arow] = besti[r];
    }
    __syncthreads();
    if (tid < 128) {
        float bv = cv[tid*33];
        int   bi = ci[tid*33];
#pragma unroll 4
        for (int j = 1; j < 32; ++j) {
            float v  = cv[tid*33 + j];
            int   ii = ci[tid*33 + j];
            if (v > bv || (v == bv && ii < bi)) { bv = v; bi = ii; }  // np first-min
        }
        idxs[tid] = bi;
        atomicAdd(&hist[bi], 1.0f);                   // exact int counts
        out[(size_t)IDX_OFF + bh0*64 + tid] = (float)bi;
    }
    __syncthreads();

    // ---- epilogue: quantized write (coalesced over w) + loss partial ----
    const int w  = tid & 63;
    const int cq = tid >> 6;              // 0..3 -> channels cq*16..cq*16+15
    float lsum = 0.f;
#pragma unroll
    for (int hf = 0; hf < 2; ++hf) {
        int p   = hf*64 + w;
        int idx = idxs[p];
        const float* ev = emb + (size_t)idx*64;
        float* outq = out + (size_t)b*(64*4096) + (size_t)(h0+hf)*64 + w;
#pragma unroll
        for (int i = 0; i < 4; ++i) {
            float4 qv = *(const float4*)(ev + cq*16 + i*4);
            float4 zv = *(const float4*)&zs[p*68 + cq*16 + i*4];
            int c = cq*16 + i*4;
            outq[(size_t)(c+0)*4096] = qv.x;
            outq[(size_t)(c+1)*4096] = qv.y;
            outq[(size_t)(c+2)*4096] = qv.z;
            outq[(size_t)(c+3)*4096] = qv.w;
            float d0 = qv.x - zv.x, d1 = qv.y - zv.y;
            float d2 = qv.z - zv.z, d3 = qv.w - zv.w;
            lsum = fmaf(d0, d0, lsum); lsum = fmaf(d1, d1, lsum);
            lsum = fmaf(d2, d2, lsum); lsum = fmaf(d3, d3, lsum);
        }
    }
#pragma unroll
    for (int off = 32; off > 0; off >>= 1)
        lsum += __shfl_xor(lsum, off, 64);
    if (lane == 0) redw[wv] = lsum;
    __syncthreads();
    if (tid == 0)
        lossp[blk] = redw[0] + redw[1] + redw[2] + redw[3];
}

// ---------------------------------------------------------------------------
// Finalize: loss + perplexity, fixed-order tree. 1 x 1024.
// ---------------------------------------------------------------------------
__global__ void vq_fin(const float* __restrict__ hist,
                       const float* __restrict__ lossp,
                       float* __restrict__ out) {
    __shared__ float sh[1024];
    __shared__ float sl[1024];
    int t = threadIdx.x;
    float hc = hist[t];
    float p  = hc * (1.0f / 65536.0f);
    sh[t] = p * logf(p + 1e-10f);
    sl[t] = (t < 512) ? lossp[t] : 0.f;
    __syncthreads();
    for (int s = 512; s > 0; s >>= 1) {
        if (t < s) { sh[t] += sh[t+s]; sl[t] += sl[t+s]; }
        __syncthreads();
    }
    if (t == 0) {
        out[LOSS_OFF] = 0.25f * sl[0] / (float)QOUT_SZ;
        out[PERP_OFF] = expf(-sh[0]);
    }
}

extern "C" void kernel_launch(void* const* d_in, const int* in_sizes, int n_in,
                              void* d_out, int out_size, void* d_ws, size_t ws_size,
                              hipStream_t stream) {
    const float* z   = (const float*)d_in[0];   // [16,64,64,64] fp32 NCHW
    const float* emb = (const float*)d_in[1];   // [1024,64] fp32
    float* out = (float*)d_out;
    char*  ws  = (char*)d_ws;

    _Float16* ehi  = (_Float16*)(ws + WS_EHI);
    _Float16* elo  = (_Float16*)(ws + WS_ELO);
    float*    esq  = (float*)(ws + WS_ESQ);
    float*    hist = (float*)(ws + WS_HIST);
    float*    lossp= (float*)(ws + WS_LOSS);

    vq_conv<<<64, 256, 0, stream>>>(emb, ehi, elo);
    vq_prep<<<4, 256, 0, stream>>>(emb, esq, hist);
    vq_main<<<512, 256, 0, stream>>>(z, emb, ehi, elo, esq, hist, lossp, out);
    vq_fin<<<1, 1024, 0, stream>>>(hist, lossp, out);
}